// Round 9
// baseline (324.177 us; speedup 1.0000x reference)
//
#include <hip/hip_runtime.h>
#include <cstddef>

#define BATCH   2
#define SEQ     2048
#define DMODEL  1024
#define NH      16
#define HDIM    64
#define WIN     256
#define MTOT    4096

typedef __bf16 bf16;
typedef __attribute__((ext_vector_type(8)))  __bf16 bf16x8;
typedef __attribute__((ext_vector_type(4)))  float  f32x4;
typedef __attribute__((ext_vector_type(16))) float  f32x16;

#define GLOAD_LDS(gp, lp) __builtin_amdgcn_global_load_lds( \
    (const __attribute__((address_space(1))) void*)(gp),    \
    (__attribute__((address_space(3))) void*)(lp), 16, 0, 0)

#define MFMA32(a, b, c) __builtin_amdgcn_mfma_f32_32x32x16_bf16(a, b, c, 0, 0, 0)

__device__ __forceinline__ float fast_exp2(float x) {
#if __has_builtin(__builtin_amdgcn_exp2f)
  return __builtin_amdgcn_exp2f(x);
#else
  float r; asm("v_exp_f32 %0, %1" : "=v"(r) : "v"(x)); return r;
#endif
}

// ---------------------------------------------------------------------------
// Merged pre-pass: split x, w1, w2 into bf16 hi/lo in one launch.
// ---------------------------------------------------------------------------
__global__ __launch_bounds__(256)
void cvt_all(const float* __restrict__ x, const float* __restrict__ w1,
             const float* __restrict__ w2, bf16* __restrict__ xh,
             bf16* __restrict__ xl, bf16* __restrict__ w1h,
             bf16* __restrict__ w1l, bf16* __restrict__ w2h,
             bf16* __restrict__ w2l) {
  const int bid = blockIdx.x;
  const float* s; bf16 *hp, *lp; int base;
  if (bid < 2048)      { s = x;  hp = xh;  lp = xl;  base = bid * 2048; }
  else if (bid < 3584) { s = w1; hp = w1h; lp = w1l; base = (bid - 2048) * 2048; }
  else                 { s = w2; hp = w2h; lp = w2l; base = (bid - 3584) * 2048; }
  const int i = base + threadIdx.x * 8;
  float4 a = *(const float4*)(s + i);
  float4 c = *(const float4*)(s + i + 4);
  const float f[8] = {a.x, a.y, a.z, a.w, c.x, c.y, c.z, c.w};
  bf16x8 vh, vl;
#pragma unroll
  for (int j = 0; j < 8; ++j) {
    bf16 hh = (bf16)f[j];
    vh[j] = hh;
    vl[j] = (bf16)(f[j] - (float)hh);
  }
  *(bf16x8*)(hp + i) = vh;
  *(bf16x8*)(lp + i) = vl;
}

// ---------------------------------------------------------------------------
// Split-bf16 MFMA GEMM. C = (Ah+Al)(Bh+Bl)^T + bias (3 MFMA) or hh-only (1).
// lda/ldb = row strides (K may be a sub-range for split-K); blockIdx.z picks
// a K-slice: z>0 writes partials to P0 (no bias), combined by add_inplace.
// mode 0: Cdst[grow*N+col] = v (fp32, col bias)          -- out-proj
// mode 1: col<1024  -> Qh/Ql row-major (hi+lo), 3 MFMA;
//         col in [1024,2048) -> K frag tiles (hh-only);
//         col >= 2048        -> V^T frag tiles (hh-only) at PT + 4M els.
// K tile elem (key,d): ((key>>5)*4+(d>>4))*512 + (((d>>3)&1)*32+(key&31))*8 + (d&7)
// V tile elem (key,d): ((d>>5)*4+((key&63)>>4))*512 + (((key>>3)&1)*32+(d&31))*8 + (key&7)
// ---------------------------------------------------------------------------
__global__ __launch_bounds__(256)
void gemm_split(const bf16* __restrict__ Ah, const bf16* __restrict__ Al,
                const bf16* __restrict__ Bh, const bf16* __restrict__ Bl,
                const float* __restrict__ bias, int K, int lda, int ldb,
                int N, int mode, float* __restrict__ Cf, bf16* __restrict__ P0,
                bf16* __restrict__ P1, bf16* __restrict__ PT) {
  __shared__ bf16 sAh[128 * 32];
  __shared__ bf16 sAl[128 * 32];
  __shared__ bf16 sBh[128 * 32];
  __shared__ bf16 sBl[128 * 32];

  const int t = threadIdx.x, w = t >> 6, lane = t & 63;
  const int ln15 = lane & 15, quad = lane >> 4;
  const int bm = blockIdx.y * 128, bn = blockIdx.x * 128;
  const int wrow = (w & 1) * 64, wcol = (w >> 1) * 64;
  const int drow = lane >> 2;
  const int dkcol = (lane & 3) * 8;
  const int kz = blockIdx.z;
  const bool cross = !(mode == 1 && bn >= 1024);   // wave-uniform

  // split-K slice
  Ah += (size_t)kz * K;  Bh += (size_t)kz * K;
  if (Al) Al += (size_t)kz * K;
  if (Bl) Bl += (size_t)kz * K;
  float* Cdst = (kz == 0) ? Cf : (float*)P0;
  const float* bz = (kz == 0) ? bias : nullptr;

  f32x4 acc[4][4];
#pragma unroll
  for (int i = 0; i < 4; ++i)
#pragma unroll
    for (int j = 0; j < 4; ++j)
#pragma unroll
      for (int r = 0; r < 4; ++r) acc[i][j][r] = 0.f;

  for (int k0 = 0; k0 < K; k0 += 32) {
    __syncthreads();
#pragma unroll
    for (int half = 0; half < 2; ++half) {
      const int r = w * 32 + half * 16 + drow;
      const size_t goffA = (size_t)(bm + r) * lda + k0 + dkcol;
      const size_t goffB = (size_t)(bn + r) * ldb + k0 + dkcol;
      const int loff = (w * 32 + half * 16) * 32;
      GLOAD_LDS(Ah + goffA, sAh + loff);
      GLOAD_LDS(Bh + goffB, sBh + loff);
      if (cross) {
        GLOAD_LDS(Al + goffA, sAl + loff);
        GLOAD_LDS(Bl + goffB, sBl + loff);
      }
    }
    __syncthreads();

    bf16x8 afh[4], afl[4], bfh[4], bfl[4];
#pragma unroll
    for (int mt = 0; mt < 4; ++mt) {
      const int off = (wrow + mt * 16 + ln15) * 32 + quad * 8;
      afh[mt] = *(const bf16x8*)&sAh[off];
      if (cross) afl[mt] = *(const bf16x8*)&sAl[off];
    }
#pragma unroll
    for (int nt = 0; nt < 4; ++nt) {
      const int off = (wcol + nt * 16 + ln15) * 32 + quad * 8;
      bfh[nt] = *(const bf16x8*)&sBh[off];
      if (cross) bfl[nt] = *(const bf16x8*)&sBl[off];
    }
#pragma unroll
    for (int mt = 0; mt < 4; ++mt)
#pragma unroll
      for (int nt = 0; nt < 4; ++nt) {
        acc[mt][nt] = __builtin_amdgcn_mfma_f32_16x16x32_bf16(afh[mt], bfh[nt], acc[mt][nt], 0, 0, 0);
        if (cross) {
          acc[mt][nt] = __builtin_amdgcn_mfma_f32_16x16x32_bf16(afh[mt], bfl[nt], acc[mt][nt], 0, 0, 0);
          acc[mt][nt] = __builtin_amdgcn_mfma_f32_16x16x32_bf16(afl[mt], bfh[nt], acc[mt][nt], 0, 0, 0);
        }
      }
  }

  float bbcol[4];
#pragma unroll
  for (int nt = 0; nt < 4; ++nt)
    bbcol[nt] = bz ? bz[bn + wcol + nt * 16 + ln15] : 0.f;

#pragma unroll
  for (int mt = 0; mt < 4; ++mt)
#pragma unroll
    for (int r = 0; r < 4; ++r) {
      const size_t grow = (size_t)(bm + wrow + mt * 16 + quad * 4 + r);
#pragma unroll
      for (int nt = 0; nt < 4; ++nt) {
        const int col = bn + wcol + nt * 16 + ln15;
        const float v = acc[mt][nt][r] + bbcol[nt];
        if (mode == 0) {
          Cdst[grow * N + col] = v;
        } else {
          if (col < 1024) {
            const bf16 hh = (bf16)v;
            P0[grow * 1024 + col] = hh;
            P1[grow * 1024 + col] = (bf16)(v - (float)hh);
          } else if (col < 2048) {
            const int btok = (int)(grow >> 11), key = (int)(grow & 2047);
            const int kt = key >> 6, kw = key & 63;
            const int hh2 = (col - 1024) >> 6, d = col & 63;
            const size_t addr = ((size_t)((btok * 16 + hh2) * 32 + kt) << 12)
                              + (((kw >> 5) * 4 + (d >> 4)) << 9)
                              + ((((d >> 3) & 1) << 5) + (kw & 31)) * 8 + (d & 7);
            PT[addr] = (bf16)v;
          } else {
            const int btok = (int)(grow >> 11), key = (int)(grow & 2047);
            const int kt = key >> 6, kw = key & 63;
            const int cv = col - 2048, hh2 = cv >> 6, d = cv & 63;
            const size_t addr = ((size_t)((btok * 16 + hh2) * 32 + kt) << 12)
                              + (((d >> 5) * 4 + (kw >> 4)) << 9)
                              + ((((kw >> 3) & 1) << 5) + (d & 31)) * 8 + (kw & 7);
            PT[(size_t)(1 << 22) + addr] = (bf16)v;
          }
        }
      }
    }
}

// ---------------------------------------------------------------------------
// out[i] += part[i]  (split-K combine), 4 floats/thread.
// ---------------------------------------------------------------------------
__global__ __launch_bounds__(256)
void add_inplace(float* __restrict__ out, const float* __restrict__ part) {
  const int i = (blockIdx.x * 256 + threadIdx.x) * 4;
  float4 a = *(const float4*)(out + i);
  float4 b = *(const float4*)(part + i);
  a.x += b.x; a.y += b.y; a.z += b.z; a.w += b.w;
  *(float4*)(out + i) = a;
}

// ---------------------------------------------------------------------------
// MFMA flash attention, software-pipelined (R8 lesson: QK->exp->PV is one
// serial chain per wave; with 2 waves/SIMD that left ~47% idle).
// Pipeline: at iter kt the wave computes S(kt+1) via MFMA (K staged 2-ahead)
// BEFORE the exp(kt) VALU block -- independent chains, so MFMA executes
// under the exp/VALU issue stream. V staged 1-ahead. 2-buffer LDS for both;
// all cross-buffer hazards are protected by the one barrier per iter.
// K/V come from frag-ordered tiles (contiguous 1KB DMA bursts).
// XCD swizzle + complementary qt pairing as R7/R8.
// ---------------------------------------------------------------------------
__global__ __launch_bounds__(256)
void attn_mfma(const bf16* __restrict__ Qh, const bf16* __restrict__ Ql,
               const bf16* __restrict__ Kt, const bf16* __restrict__ Vt,
               bf16* __restrict__ Omh, bf16* __restrict__ Oml) {
  const int t = threadIdx.x, w = t >> 6, lane = t & 63;
  const int ln31 = lane & 31, half = lane >> 5;
  const int bid = blockIdx.x;
  const int bh = ((bid >> 3) & 3) * 8 + (bid & 7);   // bid%8 == bh%8 -> XCD
  const int qi = bid >> 5;                           // 0..15
  const int qt = (qi < 8) ? qi : 23 - qi;            // complementary pairing
  const int i0 = qt * 128;
  const int b = bh >> 4, h = bh & 15;
  const int i0w = i0 + w * 32;                 // this wave's first q row
  const int lim = i0w + WIN;                   // allowed: j <= lim + rl

  __shared__ bf16 sK[2][4096];                 // K tile dbuf (8KB each)
  __shared__ bf16 sV[2][4096];                 // V tile dbuf
  __shared__ bf16 sP[128 * 72];                // wave-private rows

  // ---- Q fragments: hi+lo combined, scaled by log2(e)/8, re-split ----
  bf16x8 qh[4], ql[4];
  {
    const size_t rowQ = (size_t)(b * SEQ + i0w + ln31);
#pragma unroll
    for (int ks = 0; ks < 4; ++ks) {
      bf16x8 vh = *(const bf16x8*)(Qh + rowQ * 1024 + h * 64 + ks * 16 + half * 8);
      bf16x8 vl = *(const bf16x8*)(Ql + rowQ * 1024 + h * 64 + ks * 16 + half * 8);
#pragma unroll
      for (int j = 0; j < 8; ++j) {
        float f = ((float)vh[j] + (float)vl[j]) * 0.1803368801111204f;  // log2(e)/8
        bf16 hh = (bf16)f;
        qh[ks][j] = hh;
        ql[ks][j] = (bf16)(f - (float)hh);
      }
    }
  }
  bf16x8 onesf;
#pragma unroll
  for (int j = 0; j < 8; ++j) onesf[j] = (ln31 == 0) ? (bf16)1.0f : (bf16)0.0f;

  f32x16 accO0, accO1, accL;
#pragma unroll
  for (int r = 0; r < 16; ++r) { accO0[r] = 0.f; accO1[r] = 0.f; accL[r] = 0.f; }

  const bf16* KtBH = Kt + ((size_t)(b * 16 + h) << 17);
  const bf16* VtBH = Vt + ((size_t)(b * 16 + h) << 17);
  const int lane8 = lane * 8;

  const int nkt_b = min((i0 + 127 + WIN) / 64 + 1, SEQ / 64);   // block iters
  const int nkt_w = min((i0w + 31 + WIN) / 64 + 1, SEQ / 64);   // wave iters

  auto stageK = [&](int kt, int bs) {
    const size_t toff = ((size_t)kt << 12) + lane8;
#pragma unroll
    for (int ii = 0; ii < 2; ++ii) {
      const int s = w * 2 + ii;
      GLOAD_LDS(KtBH + toff + ((size_t)s << 9), &sK[bs][s << 9]);
    }
  };
  auto stageV = [&](int kt, int bs) {
    const size_t toff = ((size_t)kt << 12) + lane8;
#pragma unroll
    for (int ii = 0; ii < 2; ++ii) {
      const int s = w * 2 + ii;
      GLOAD_LDS(VtBH + toff + ((size_t)s << 9), &sV[bs][s << 9]);
    }
  };
  auto qk = [&](int kt, f32x16& R0, f32x16& R1) {
    const bf16* Kb = sK[kt & 1];
#pragma unroll
    for (int r = 0; r < 16; ++r) { R0[r] = 0.f; R1[r] = 0.f; }
#pragma unroll
    for (int ks = 0; ks < 4; ++ks) {
      bf16x8 k0 = *(const bf16x8*)&Kb[(ks << 9) + lane8];
      bf16x8 k1 = *(const bf16x8*)&Kb[((4 + ks) << 9) + lane8];
      R0 = MFMA32(qh[ks], k0, R0);
      R0 = MFMA32(ql[ks], k0, R0);
      R1 = MFMA32(qh[ks], k1, R1);
      R1 = MFMA32(ql[ks], k1, R1);
    }
  };

  f32x16 S0, S1, T0, T1;
  stageK(0, 0);
  stageV(0, 0);
  __syncthreads();        // K(0), V(0) ready
  qk(0, S0, S1);
  stageK(1, 1);           // drained by the loop's first barrier

  for (int kt = 0; kt < nkt_b; ++kt) {
    __syncthreads();      // drains K(kt+1) [issued kt-1] and V(kt) [issued kt-1]
    if (kt + 1 < nkt_w) qk(kt + 1, T0, T1);        // MFMA, indep of exp(kt)
    if (kt + 2 < nkt_b) stageK(kt + 2, kt & 1);    // overwrites dead K(kt)
    if (kt + 1 < nkt_b) stageV(kt + 1, (kt + 1) & 1);
    if (kt < nkt_w) {     // wave-uniform tail skip
      const int j0 = kt * 64;
      // ---- softmax: p = exp2(s); mask -> 0 after exp; write P to LDS ----
#pragma unroll
      for (int c = 0; c < 2; ++c) {
        f32x16& S = c ? S1 : S0;
        const int vj = j0 + c * 32 + ln31 - lim;   // mask if vj > rl
        const bool may = (j0 + c * 32 + 31) > lim;
#pragma unroll
        for (int r = 0; r < 16; ++r) {
          const int rl = (r & 3) + 8 * (r >> 2) + 4 * half;
          float pv = fast_exp2(S[r]);
          if (may && (vj > rl)) pv = 0.f;
          sP[(w * 32 + rl) * 72 + c * 32 + ln31] = (bf16)pv;
        }
      }
      // ---- O += P V ; l += P 1 ----
      const bf16* Vb = sV[kt & 1];
#pragma unroll
      for (int ks = 0; ks < 4; ++ks) {
        bf16x8 pA = *(const bf16x8*)&sP[(w * 32 + ln31) * 72 + ks * 16 + half * 8];
        bf16x8 v0 = *(const bf16x8*)&Vb[(ks << 9) + lane8];
        bf16x8 v1 = *(const bf16x8*)&Vb[((4 + ks) << 9) + lane8];
        accO0 = MFMA32(pA, v0, accO0);
        accO1 = MFMA32(pA, v1, accO1);
        accL  = MFMA32(pA, onesf, accL);
      }
    }
    S0 = T0; S1 = T1;
  }

  // ---- epilogue: O /= l, write Om hi/lo ----
#pragma unroll
  for (int r = 0; r < 16; ++r) {
    const int rl = (r & 3) + 8 * (r >> 2) + 4 * half;
    const float lv = __shfl(accL[r], lane & 32, 64);
    const float inv = 1.0f / lv;
    const size_t grow = (size_t)(b * SEQ + i0w + rl);
    const int col0 = h * 64 + ln31;
    const float v0 = accO0[r] * inv;
    const float v1 = accO1[r] * inv;
    const bf16 h0 = (bf16)v0, h1 = (bf16)v1;
    Omh[grow * DMODEL + col0]      = h0;
    Oml[grow * DMODEL + col0]      = (bf16)(v0 - (float)h0);
    Omh[grow * DMODEL + col0 + 32] = h1;
    Oml[grow * DMODEL + col0 + 32] = (bf16)(v1 - (float)h1);
  }
}

// ---------------------------------------------------------------------------
extern "C" void kernel_launch(void* const* d_in, const int* in_sizes, int n_in,
                              void* d_out, int out_size, void* d_ws, size_t ws_size,
                              hipStream_t stream) {
  const float* x  = (const float*)d_in[0];
  const float* w1 = (const float*)d_in[1];
  const float* b1 = (const float*)d_in[2];
  const float* w2 = (const float*)d_in[3];
  const float* b2 = (const float*)d_in[4];
  float* out = (float*)d_out;

  char* ws = (char*)d_ws;
  bf16* Qh   = (bf16*)(ws + 0);          // [4096][1024]
  bf16* Ql   = (bf16*)(ws + 8388608);    // [4096][1024]
  bf16* Kt   = (bf16*)(ws + 16777216);   // K frag tiles, 8 MB (Vt follows)
  bf16* Vt   = (bf16*)(ws + 25165824);   // V frag tiles, 8 MB (= Kt + 4M els)
  bf16* xh   = (bf16*)(ws + 33554432);   // [4096][1024]
  bf16* xl   = (bf16*)(ws + 41943040);
  bf16* w1h  = (bf16*)(ws + 50331648);   // [3072][1024]
  bf16* w1l  = (bf16*)(ws + 56623104);
  bf16* w2h  = (bf16*)(ws + 62914560);   // [1024][1024]
  bf16* w2l  = (bf16*)(ws + 65011712);
  bf16* Omh  = xh;                       // reuse (x dead after gemm1)
  bf16* Oml  = xl;
  float* part1 = (float*)(ws + 0);       // reuse Qh/Ql (dead after attn)

  cvt_all<<<dim3(4096), 256, 0, stream>>>(x, w1, w2, xh, xl, w1h, w1l, w2h, w2l);

  // fused QKV projection: x @ w1^T + b1 -> Q (hi/lo, 3 MFMA),
  // K frag tiles (hh), V^T frag tiles (hh). grid 768 = 3 blocks/CU.
  gemm_split<<<dim3(3072 / 128, MTOT / 128), 256, 0, stream>>>(
      xh, xl, w1h, w1l, b1, DMODEL, DMODEL, DMODEL, 3072, 1,
      nullptr, Qh, Ql, Kt);

  attn_mfma<<<dim3(512), 256, 0, stream>>>(Qh, Ql, Kt, Vt, Omh, Oml);

  // out-proj, split-K x2 (z=0 -> out with bias, z=1 -> part1), then combine
  gemm_split<<<dim3(DMODEL / 128, MTOT / 128, 2), 256, 0, stream>>>(
      Omh, Oml, w2h, w2l, b2, 512, DMODEL, DMODEL, DMODEL, 0,
      out, (bf16*)part1, nullptr, nullptr);
  add_inplace<<<dim3(MTOT * DMODEL / 1024), 256, 0, stream>>>(out, part1);
}